// Round 9
// baseline (1653.921 us; speedup 1.0000x reference)
//
#include <hip/hip_runtime.h>
#include <hip/hip_bf16.h>

#define V_DIM 128256
#define K_DIM 2048
#define M_DIM 2048
#define NBX   (V_DIM / 256)  // 501 n-tiles
#define NPB   NBX            // partial granularity = 256 cols
#define NT    (K_DIM / 64)   // 32 K-tiles

using f32x4  = __attribute__((ext_vector_type(4))) float;
using bf16x8 = __attribute__((ext_vector_type(8))) short;

// round-to-nearest-even f32 -> bf16 (as ushort)
static __device__ __forceinline__ unsigned short f2b(float f) {
  unsigned int x = __float_as_uint(f);
  unsigned int r = (x + 0x7fffu + ((x >> 16) & 1u)) >> 16;
  return (unsigned short)r;
}

// ---------------- x f32 -> bf16 ----------------
__global__ __launch_bounds__(256) void cvt_x(const float* __restrict__ x,
                                             unsigned short* __restrict__ xb) {
  const size_t i = ((size_t)blockIdx.x * 256 + threadIdx.x) * 8;
  const float4 a = *(const float4*)&x[i];
  const float4 b = *(const float4*)&x[i + 4];
  union { unsigned short u[8]; uint4 v; } o;
  o.u[0] = f2b(a.x); o.u[1] = f2b(a.y); o.u[2] = f2b(a.z); o.u[3] = f2b(a.w);
  o.u[4] = f2b(b.x); o.u[5] = f2b(b.y); o.u[6] = f2b(b.z); o.u[7] = f2b(b.w);
  *(uint4*)&xb[i] = o.v;
}

// ---------------- 256x256 GEMM + in-kernel W transpose + partial sum-of-exp + target ----
// Round-3 proven barrier skeleton (4 phases/tile, 2 barriers each).
// B operand staged from W[k][v] f32 directly: per thread (col=tid&255, h=tid>>8):
//   g0: 16 dword loads k=[tile*64 + h*32 .. +15]   issued ph0 (for tile t+1)
//   g1: 16 dword loads k=[.. +16..31]              issued ph2
//   cvt(f32->bf16 pairs) + 2x ds_write_b128 into swizzled Bl slots.
// vmcnt ledger (per wave, steady): ph2 vmcnt(1), ph3 vmcnt(1); never 0; leftover
// {A(t+1)Q1, A(t+1)Q2} invariant. All of tile t+1 resident before its barrier.
// FIX vs round 8: STAGE_A LDS offset is rb_*64 shorts (rb_ is a ROW index),
// not rb_*512 (that was an out-of-bounds write corrupting Bl -> NaN).
#define MF(a, b, c) __builtin_amdgcn_mfma_f32_16x16x32_bf16(a, b, c, 0, 0, 0)

#define STAGE_A(T, q, d) do {                                                   \
    const int rb_ = 32 * (q) + (w & 3) * 8 + (w >> 2) * 128;                    \
    __builtin_amdgcn_global_load_lds(                                           \
        (const __attribute__((address_space(1))) void*)                         \
            &xb[(size_t)(m0 + rb_ + lr) * K_DIM + (T) * 64 + sw8],              \
        (__attribute__((address_space(3))) void*)&Al[d][rb_ * 64], 16, 0, 0);   \
  } while (0)

#define RD_A(c, mi, s) (*(const bf16x8*)&Al[c][(wm * 128 + (mi) * 16 + (l & 15)) * 64 + \
                                               ((((s) * 4 + (l >> 4)) ^ (l & 7)) * 8)])
#define RD_B(c, ni, s) (*(const bf16x8*)&Bl[c][(wn * 64 + (ni) * 16 + (l & 15)) * 64 + \
                                               ((((s) * 4 + (l >> 4)) ^ (l & 7)) * 8)])

#define MFMA8(mi, aa0, aa1)                                        \
  acc[mi][0] = MF(aa0, bfr[0][0], acc[mi][0]);                     \
  acc[mi][0] = MF(aa1, bfr[0][1], acc[mi][0]);                     \
  acc[mi][1] = MF(aa0, bfr[1][0], acc[mi][1]);                     \
  acc[mi][1] = MF(aa1, bfr[1][1], acc[mi][1]);                     \
  acc[mi][2] = MF(aa0, bfr[2][0], acc[mi][2]);                     \
  acc[mi][2] = MF(aa1, bfr[2][1], acc[mi][2]);                     \
  acc[mi][3] = MF(aa0, bfr[3][0], acc[mi][3]);                     \
  acc[mi][3] = MF(aa1, bfr[3][1], acc[mi][3]);

#define MFMA_HALF(q, s, A0, A1)                                    \
  acc[2*(q)][0]   = MF(A0, bfr[0][s], acc[2*(q)][0]);              \
  acc[2*(q)+1][0] = MF(A1, bfr[0][s], acc[2*(q)+1][0]);            \
  acc[2*(q)][1]   = MF(A0, bfr[1][s], acc[2*(q)][1]);              \
  acc[2*(q)+1][1] = MF(A1, bfr[1][s], acc[2*(q)+1][1]);            \
  acc[2*(q)][2]   = MF(A0, bfr[2][s], acc[2*(q)][2]);              \
  acc[2*(q)+1][2] = MF(A1, bfr[2][s], acc[2*(q)+1][2]);            \
  acc[2*(q)][3]   = MF(A0, bfr[3][s], acc[2*(q)][3]);              \
  acc[2*(q)+1][3] = MF(A1, bfr[3][s], acc[2*(q)+1][3]);

#define LGKM(n) asm volatile("s_waitcnt lgkmcnt(" #n ")" ::: "memory"); \
                __builtin_amdgcn_sched_barrier(0)

// issue 16 B dword loads (running pointer; self-advancing by 16 rows)
#define BISSUE() do {                              \
    const float* p_ = wpp;                         \
    _Pragma("unroll")                              \
    for (int j_ = 0; j_ < 16; ++j_) {              \
      bg[j_] = *p_;                                \
      p_ += V_DIM;                                 \
    }                                              \
    wpp += (size_t)16 * V_DIM;                     \
  } while (0)

// convert bg[16] -> 16 bf16, write 2x b128 into swizzled Bl[d]
#define BCVTW(g, d) do {                                                        \
    union { __hip_bfloat162 h2[4]; uint4 v4; } p0_, p1_;                        \
    _Pragma("unroll")                                                           \
    for (int j_ = 0; j_ < 4; ++j_) {                                            \
      p0_.h2[j_] = __float22bfloat162_rn(make_float2(bg[2 * j_], bg[2 * j_ + 1]));      \
      p1_.h2[j_] = __float22bfloat162_rn(make_float2(bg[8 + 2 * j_], bg[9 + 2 * j_]));  \
    }                                                                           \
    char* bb_ = (char*)&Bl[d][0];                                               \
    *(uint4*)(bb_ + (bwr ^ ((g) * 32)))      = p0_.v4;                          \
    *(uint4*)(bb_ + (bwr ^ ((g) * 32) ^ 16)) = p1_.v4;                          \
  } while (0)

__global__ __launch_bounds__(512, 2) void gemm_lse(const unsigned short* __restrict__ xb,
                                                   const float* __restrict__ wgt,
                                                   const int* __restrict__ labels,
                                                   float* __restrict__ partial,
                                                   float* __restrict__ tgt) {
  __shared__ unsigned short Al[2][256 * 64];
  __shared__ unsigned short Bl[2][256 * 64];
  __shared__ int larr[256];

  const int tid = threadIdx.x;
  const int w = tid >> 6, l = tid & 63;
  const int wm = w >> 2, wn = w & 3;

  // bijective XCD swizzle (nwg = 4008, %8==0). Each XCD gets a contiguous
  // swz band -> the 8 m-siblings of an n-panel are consecutive on ONE XCD
  // (W panel read 8x from the same L2).
  const int swz = (blockIdx.x & 7) * (NBX * 8 >> 3) + (blockIdx.x >> 3);
  const int m0 = (swz & 7) * 256;
  const int n0 = (swz >> 3) * 256;

  const int lr = l >> 3;
  const int sw8 = ((l & 7) ^ lr) * 8;

  // B staging assignment: col cB, k-half hB
  const int cB = tid & 255;
  const int hB = tid >> 8;
  const float* wpp = wgt + (size_t)hB * 32 * V_DIM + (n0 + cB);
  const int bwr = cB * 128 + (((hB * 4) ^ (cB & 7)) * 16);
  float bg[16];

  f32x4 acc[8][4] = {};
  bf16x8 bfr[4][2];

  if (tid < 256) larr[tid] = labels[m0 + tid];

  // ---- prologue: A(0) full, B(0) g0+g1, A(1)Q0-2 in flight ----
  STAGE_A(0, 0, 0); STAGE_A(0, 1, 0); STAGE_A(0, 2, 0); STAGE_A(0, 3, 0);
  BISSUE();                    // g0(0)
  STAGE_A(1, 0, 1);
  asm volatile("s_waitcnt vmcnt(1)" ::: "memory");   // retire A(0)+g0, keep A(1)Q0
  BCVTW(0, 0);
  BISSUE();                    // g1(0)
  STAGE_A(1, 1, 1);
  asm volatile("s_waitcnt vmcnt(1)" ::: "memory");   // retire g1+A(1)Q0, keep A(1)Q1
  BCVTW(1, 0);
  wpp += (size_t)32 * V_DIM;   // skip other k-half -> next tile's range
  STAGE_A(1, 2, 1);
  asm volatile("s_waitcnt lgkmcnt(0)" ::: "memory"); // B(0) writes visible
  __builtin_amdgcn_s_barrier();

#pragma unroll 1
  for (int t = 0; t < NT; ++t) {
    const int cb = t & 1;
    // ---- phase 0: all B-frags + A Q0; issue B(t+1)g0; stage A(t+1)Q3 ----
    {
      bfr[0][0] = RD_B(cb, 0, 0); bfr[1][0] = RD_B(cb, 1, 0);
      bfr[2][0] = RD_B(cb, 2, 0); bfr[3][0] = RD_B(cb, 3, 0);
      bf16x8 a0 = RD_A(cb, 0, 0), a2 = RD_A(cb, 1, 0);
      __builtin_amdgcn_sched_barrier(0);
      bfr[0][1] = RD_B(cb, 0, 1); bfr[1][1] = RD_B(cb, 1, 1);
      bfr[2][1] = RD_B(cb, 2, 1); bfr[3][1] = RD_B(cb, 3, 1);
      bf16x8 a1 = RD_A(cb, 0, 1), a3 = RD_A(cb, 1, 1);
      if (t + 1 < NT) { BISSUE(); STAGE_A(t + 1, 3, cb ^ 1); }
      __builtin_amdgcn_s_barrier();
      LGKM(6);
      __builtin_amdgcn_s_setprio(1);
      MFMA_HALF(0, 0, a0, a2);
      LGKM(0);
      MFMA_HALF(0, 1, a1, a3);
      __builtin_amdgcn_s_setprio(0);
      __builtin_amdgcn_s_barrier();
    }
    // ---- phase 1: A Q1; stage A(t+2)Q0 ----
    {
      bf16x8 a0 = RD_A(cb, 2, 0), a1 = RD_A(cb, 2, 1);
      bf16x8 a2 = RD_A(cb, 3, 0), a3 = RD_A(cb, 3, 1);
      if (t + 2 < NT) STAGE_A(t + 2, 0, cb);
      __builtin_amdgcn_s_barrier();
      asm volatile("s_waitcnt lgkmcnt(0)" ::: "memory");
      __builtin_amdgcn_s_setprio(1);
      MFMA8(2, a0, a1);
      MFMA8(3, a2, a3);
      __builtin_amdgcn_s_setprio(0);
      __builtin_amdgcn_s_barrier();
    }
    // ---- phase 2: A Q2; retire+write B g0; issue g1; stage A(t+2)Q1 ----
    {
      bf16x8 a0 = RD_A(cb, 4, 0), a1 = RD_A(cb, 4, 1);
      bf16x8 a2 = RD_A(cb, 5, 0), a3 = RD_A(cb, 5, 1);
      if (t + 1 < NT) {
        if (t + 2 < NT) asm volatile("s_waitcnt vmcnt(1)" ::: "memory");
        else            asm volatile("s_waitcnt vmcnt(0)" ::: "memory");
        BCVTW(0, cb ^ 1);
        BISSUE();                    // g1(t+1)
        wpp += (size_t)32 * V_DIM;
      }
      if (t + 2 < NT) STAGE_A(t + 2, 1, cb);
      __builtin_amdgcn_s_barrier();
      asm volatile("s_waitcnt lgkmcnt(0)" ::: "memory");
      __builtin_amdgcn_s_setprio(1);
      MFMA8(4, a0, a1);
      MFMA8(5, a2, a3);
      __builtin_amdgcn_s_setprio(0);
      __builtin_amdgcn_s_barrier();
    }
    // ---- phase 3: A Q3; retire+write B g1; stage A(t+2)Q2; open t+1 ----
    {
      bf16x8 a0 = RD_A(cb, 6, 0), a1 = RD_A(cb, 6, 1);
      bf16x8 a2 = RD_A(cb, 7, 0), a3 = RD_A(cb, 7, 1);
      if (t + 1 < NT) {
        if (t + 2 < NT) asm volatile("s_waitcnt vmcnt(1)" ::: "memory");
        else            asm volatile("s_waitcnt vmcnt(0)" ::: "memory");
        BCVTW(1, cb ^ 1);
      }
      if (t + 2 < NT) STAGE_A(t + 2, 2, cb);
      asm volatile("s_waitcnt lgkmcnt(0)" ::: "memory");  // B writes visible pre-barrier
      __builtin_amdgcn_s_barrier();
      asm volatile("s_waitcnt lgkmcnt(0)" ::: "memory");
      __builtin_amdgcn_s_setprio(1);
      MFMA8(6, a0, a1);
      MFMA8(7, a2, a3);
      __builtin_amdgcn_s_setprio(0);
      __builtin_amdgcn_s_barrier();
    }
  }

  // ---- target extraction: thread slot (mi,ni,r) owns logit[row][col] ----
  {
    const int colbase = wn * 64 + (l & 15);
#pragma unroll
    for (int mi = 0; mi < 8; ++mi)
#pragma unroll
      for (int r = 0; r < 4; ++r) {
        const int row = wm * 128 + mi * 16 + (l >> 4) * 4 + r;
        int lab = larr[row];
        lab = lab < 0 ? 0 : (lab >= V_DIM ? V_DIM - 1 : lab);
        const int cl = lab - n0;
#pragma unroll
        for (int ni = 0; ni < 4; ++ni)
          if (cl == colbase + ni * 16) tgt[m0 + row] = acc[mi][ni][r];
      }
  }

  // ---- epilogue: per-row sum of exp over this block's 256 cols ----
  float rs[8][4];
#pragma unroll
  for (int mi = 0; mi < 8; ++mi)
#pragma unroll
    for (int r = 0; r < 4; ++r) {
      float s = 0.f;
#pragma unroll
      for (int ni = 0; ni < 4; ++ni)
        s += exp2f(acc[mi][ni][r] * 1.4426950408889634f);
#pragma unroll
      for (int off = 1; off <= 8; off <<= 1) s += __shfl_xor(s, off, 64);
      rs[mi][r] = s;
    }
  __syncthreads();
  float* red = (float*)&Al[0][0];  // [4 wn][256 rows]
  if ((l & 15) == 0) {
#pragma unroll
    for (int mi = 0; mi < 8; ++mi)
#pragma unroll
      for (int r = 0; r < 4; ++r)
        red[wn * 256 + wm * 128 + mi * 16 + (l >> 4) * 4 + r] = rs[mi][r];
  }
  __syncthreads();
  if (tid < 256) {
    const float tot = (red[tid] + red[256 + tid]) + (red[512 + tid] + red[768 + tid]);
    partial[(size_t)(m0 + tid) * NPB + (swz >> 3)] = tot;
  }
}

// ---------------- final reduce ----------------
__global__ __launch_bounds__(256) void reduce_lse(const float* __restrict__ partial,
                                                  const float* __restrict__ tgt,
                                                  const int* __restrict__ labels,
                                                  float* __restrict__ out) {
  const int row = blockIdx.x;
  float s = 0.f;
  for (int vb = threadIdx.x; vb < NPB; vb += 256)
    s += partial[(size_t)row * NPB + vb];
#pragma unroll
  for (int off = 1; off < 64; off <<= 1) s += __shfl_xor(s, off, 64);
  __shared__ float w4[4];
  if ((threadIdx.x & 63) == 0) w4[threadIdx.x >> 6] = s;
  __syncthreads();
  if (threadIdx.x == 0) {
    const float tot = (w4[0] + w4[1]) + (w4[2] + w4[3]);
    const float lse = logf(tot);
    const float loss = (labels[row] != -100) ? (lse - tgt[row]) : 0.f;
    out[row] = loss;
    out[M_DIM + row] = lse;
  }
}

extern "C" void kernel_launch(void* const* d_in, const int* in_sizes, int n_in,
                              void* d_out, int out_size, void* d_ws, size_t ws_size,
                              hipStream_t stream) {
  const float* x = (const float*)d_in[0];
  const float* wgt = (const float*)d_in[1];
  const int* labels = (const int*)d_in[2];
  float* out = (float*)d_out;

  char* ws = (char*)d_ws;
  unsigned short* xb = (unsigned short*)ws;
  size_t off = (size_t)M_DIM * K_DIM * 2;  // 8 MB
  float* partial = (float*)(ws + off);
  off += (size_t)M_DIM * NPB * 4;          // 4.1 MB
  float* tgt = (float*)(ws + off);

  cvt_x<<<dim3(M_DIM * K_DIM / (256 * 8)), dim3(256), 0, stream>>>(x, xb);
  gemm_lse<<<dim3(NBX * 8), dim3(512), 0, stream>>>(xb, wgt, labels, partial, tgt);
  reduce_lse<<<dim3(M_DIM), dim3(256), 0, stream>>>(partial, tgt, labels, out);
}

// Round 10
// 1258.844 us; speedup vs baseline: 1.3138x; 1.3138x over previous
//
#include <hip/hip_runtime.h>

#define V_DIM 128256
#define K_DIM 2048
#define M_DIM 2048
#define NPB (V_DIM / 256)  // 501 vocab blocks of 256
#define NT (K_DIM / 64)    // 32 K-tiles

using f32x4  = __attribute__((ext_vector_type(4))) float;
using bf16x8 = __attribute__((ext_vector_type(8))) short;

// round-to-nearest-even f32 -> bf16 (as ushort)
static __device__ __forceinline__ unsigned short f2b(float f) {
  unsigned int x = __float_as_uint(f);
  unsigned int r = (x + 0x7fffu + ((x >> 16) & 1u)) >> 16;
  return (unsigned short)r;
}

// ---------------- x f32 -> bf16 ----------------
__global__ __launch_bounds__(256) void cvt_x(const float* __restrict__ x,
                                             unsigned short* __restrict__ xb) {
  const size_t i = ((size_t)blockIdx.x * 256 + threadIdx.x) * 8;
  const float4 a = *(const float4*)&x[i];
  const float4 b = *(const float4*)&x[i + 4];
  union { unsigned short u[8]; uint4 v; } o;
  o.u[0] = f2b(a.x); o.u[1] = f2b(a.y); o.u[2] = f2b(a.z); o.u[3] = f2b(a.w);
  o.u[4] = f2b(b.x); o.u[5] = f2b(b.y); o.u[6] = f2b(b.z); o.u[7] = f2b(b.w);
  *(uint4*)&xb[i] = o.v;
}

// ---------------- W chunk transpose: [K][V] f32 -> [cc][K] bf16 ----------------
__global__ __launch_bounds__(256) void transpose_w(const float* __restrict__ wgt,
                                                   unsigned short* __restrict__ wtc,
                                                   int c0) {
  __shared__ unsigned short tile[64][65];
  const int t  = threadIdx.x;
  const int cb = blockIdx.x * 64;
  const int kb = blockIdx.y * 64;
  const int tc4 = (t & 15) * 4;
  const int tk  = t >> 4;
#pragma unroll
  for (int p = 0; p < 4; ++p) {
    const int k = kb + tk + p * 16;
    const float4 v = *(const float4*)&wgt[(size_t)k * V_DIM + (c0 + cb + tc4)];
    tile[tc4 + 0][tk + p * 16] = f2b(v.x);
    tile[tc4 + 1][tk + p * 16] = f2b(v.y);
    tile[tc4 + 2][tk + p * 16] = f2b(v.z);
    tile[tc4 + 3][tk + p * 16] = f2b(v.w);
  }
  __syncthreads();
  const int wk4 = (t & 15) * 4;
  const int wc  = t >> 4;
#pragma unroll
  for (int p = 0; p < 4; ++p) {
    const int c = wc + p * 16;
    ushort4 o;
    o.x = tile[c][wk4 + 0];
    o.y = tile[c][wk4 + 1];
    o.z = tile[c][wk4 + 2];
    o.w = tile[c][wk4 + 3];
    *(ushort4*)&wtc[(size_t)(cb + c) * K_DIM + (kb + wk4)] = o;
  }
}

// ---------------- 256x256 2-phase GEMM + partial sum-of-exp + target ----------------
// Round-10 structure: 2 phases/tile, ONE barrier per phase (end-barrier only).
// Safety: (a) residency: vmcnt(4) before phB end-barrier retires ALL of tile
// t+1 (FIFO: [t+1 x8, t+2 x4] outstanding); (b) WAR: every stage targets a
// region whose readers retired (per-wave lgkm(0)) before the previous
// end-barrier. No ds_writes in loop => no other cross-wave hazards.
#define MF(a, b, c) __builtin_amdgcn_mfma_f32_16x16x32_bf16(a, b, c, 0, 0, 0)

#define STAGE_A(T, q, d) do {                                                   \
    const int rb_ = 32 * (q) + (w & 3) * 8 + (w >> 2) * 128;                    \
    __builtin_amdgcn_global_load_lds(                                           \
        (const __attribute__((address_space(1))) void*)                         \
            &xb[(size_t)(m0 + rb_ + lr) * K_DIM + (T) * 64 + sw8],              \
        (__attribute__((address_space(3))) void*)&Al[d][rb_ * 64], 16, 0, 0);   \
  } while (0)

#define STAGE_B(T, i, d) do {                                                   \
    const int rb_ = (i) * 64 + w * 8;                                           \
    __builtin_amdgcn_global_load_lds(                                           \
        (const __attribute__((address_space(1))) void*)                         \
            &wt[(size_t)(n0 + rb_ + lr) * K_DIM + (T) * 64 + sw8],              \
        (__attribute__((address_space(3))) void*)&Bl[d][rb_ * 64], 16, 0, 0);   \
  } while (0)

#define RD_A(c, mi, s) (*(const bf16x8*)&Al[c][(wm * 128 + (mi) * 16 + (l & 15)) * 64 + \
                                               ((((s) * 4 + (l >> 4)) ^ (l & 7)) * 8)])
#define RD_B(c, ni, s) (*(const bf16x8*)&Bl[c][(wn * 64 + (ni) * 16 + (l & 15)) * 64 + \
                                               ((((s) * 4 + (l >> 4)) ^ (l & 7)) * 8)])

#define MFMA8(mi, aa0, aa1)                                        \
  acc[mi][0] = MF(aa0, bfr[0][0], acc[mi][0]);                     \
  acc[mi][0] = MF(aa1, bfr[0][1], acc[mi][0]);                     \
  acc[mi][1] = MF(aa0, bfr[1][0], acc[mi][1]);                     \
  acc[mi][1] = MF(aa1, bfr[1][1], acc[mi][1]);                     \
  acc[mi][2] = MF(aa0, bfr[2][0], acc[mi][2]);                     \
  acc[mi][2] = MF(aa1, bfr[2][1], acc[mi][2]);                     \
  acc[mi][3] = MF(aa0, bfr[3][0], acc[mi][3]);                     \
  acc[mi][3] = MF(aa1, bfr[3][1], acc[mi][3]);

#define LGKM(n) asm volatile("s_waitcnt lgkmcnt(" #n ")" ::: "memory"); \
                __builtin_amdgcn_sched_barrier(0)

__global__ __launch_bounds__(512, 2) void gemm_lse(const unsigned short* __restrict__ xb,
                                                   const unsigned short* __restrict__ wt,
                                                   const int* __restrict__ labels,
                                                   float* __restrict__ partial,
                                                   float* __restrict__ tgt,
                                                   int c0, int nbx) {
  __shared__ unsigned short Al[2][256 * 64];
  __shared__ unsigned short Bl[2][256 * 64];
  __shared__ int larr[256];

  const int tid = threadIdx.x;
  const int w = tid >> 6, l = tid & 63;
  const int wm = w >> 2, wn = w & 3;

  // bijective XCD swizzle (nwg = nbx*8, always %8==0); 8 consecutive share B-panel
  const int nwg = nbx * 8;
  const int swz = (blockIdx.x & 7) * (nwg >> 3) + (blockIdx.x >> 3);
  const int m0 = (swz & 7) * 256;
  const int n0 = (swz >> 3) * 256;   // chunk-local
  const int gn0 = c0 + n0;           // global vocab col base

  const int lr = l >> 3;
  const int sw8 = ((l & 7) ^ lr) * 8;

  f32x4 acc[8][4] = {};
  bf16x8 bfr[4][2];

  if (tid < 256) larr[tid] = labels[m0 + tid];

  // prologue: tile0 all 8 + tile1 {Q0,I0,Q1,I1}; retire tile0, keep tile1's 4
  STAGE_A(0, 0, 0); STAGE_B(0, 0, 0); STAGE_A(0, 1, 0); STAGE_B(0, 1, 0);
  STAGE_A(0, 2, 0); STAGE_B(0, 2, 0); STAGE_A(0, 3, 0); STAGE_B(0, 3, 0);
  STAGE_A(1, 0, 1); STAGE_B(1, 0, 1);
  STAGE_A(1, 1, 1); STAGE_B(1, 1, 1);
  asm volatile("s_waitcnt vmcnt(4)" ::: "memory");
  __builtin_amdgcn_s_barrier();

#pragma unroll 1
  for (int t = 0; t < NT; ++t) {
    const int cb = t & 1;
    // ---------- phase A: quarters 0,1 (32 MFMA) ----------
    {
      // group1 (12): all B + A mi0,mi1
      bfr[0][0] = RD_B(cb, 0, 0); bfr[1][0] = RD_B(cb, 1, 0);
      bfr[2][0] = RD_B(cb, 2, 0); bfr[3][0] = RD_B(cb, 3, 0);
      bfr[0][1] = RD_B(cb, 0, 1); bfr[1][1] = RD_B(cb, 1, 1);
      bfr[2][1] = RD_B(cb, 2, 1); bfr[3][1] = RD_B(cb, 3, 1);
      bf16x8 a00 = RD_A(cb, 0, 0), a01 = RD_A(cb, 0, 1);
      bf16x8 a10 = RD_A(cb, 1, 0), a11 = RD_A(cb, 1, 1);
      __builtin_amdgcn_sched_barrier(0);
      // group2 (4): A mi2,mi3
      bf16x8 a20 = RD_A(cb, 2, 0), a21 = RD_A(cb, 2, 1);
      bf16x8 a30 = RD_A(cb, 3, 0), a31 = RD_A(cb, 3, 1);
      // stage t+1 {Q2,I2,Q3,I3} -> cb^1 (readers retired before prev barrier)
      if (t + 1 < NT) {
        STAGE_A(t + 1, 2, cb ^ 1); STAGE_B(t + 1, 2, cb ^ 1);
        STAGE_A(t + 1, 3, cb ^ 1); STAGE_B(t + 1, 3, cb ^ 1);
      }
      LGKM(4);  // group1 retired; group2 lands under q0 MFMAs
      __builtin_amdgcn_s_setprio(1);
      MFMA8(0, a00, a01);
      MFMA8(1, a10, a11);
      LGKM(0);
      MFMA8(2, a20, a21);
      MFMA8(3, a30, a31);
      __builtin_amdgcn_s_setprio(0);
      __builtin_amdgcn_s_barrier();
    }
    // ---------- phase B: quarters 2,3 (32 MFMA) ----------
    {
      bf16x8 a40 = RD_A(cb, 4, 0), a41 = RD_A(cb, 4, 1);
      bf16x8 a50 = RD_A(cb, 5, 0), a51 = RD_A(cb, 5, 1);
      __builtin_amdgcn_sched_barrier(0);
      bf16x8 a60 = RD_A(cb, 6, 0), a61 = RD_A(cb, 6, 1);
      bf16x8 a70 = RD_A(cb, 7, 0), a71 = RD_A(cb, 7, 1);
      // stage t+2 {Q0,I0,Q1,I1} -> cb (readers retired before prev barrier)
      if (t + 2 < NT) {
        STAGE_A(t + 2, 0, cb); STAGE_B(t + 2, 0, cb);
        STAGE_A(t + 2, 1, cb); STAGE_B(t + 2, 1, cb);
      }
      LGKM(4);  // mi4,5 retired; mi6,7 land under q2 MFMAs
      __builtin_amdgcn_s_setprio(1);
      MFMA8(4, a40, a41);
      MFMA8(5, a50, a51);
      LGKM(0);
      MFMA8(6, a60, a61);
      MFMA8(7, a70, a71);
      __builtin_amdgcn_s_setprio(0);
      // residency for tile t+1: retire its 8 stages (keep t+2's 4)
      if (t + 2 < NT) asm volatile("s_waitcnt vmcnt(4)" ::: "memory");
      else            asm volatile("s_waitcnt vmcnt(0)" ::: "memory");
      __builtin_amdgcn_s_barrier();
    }
  }

  // ---- target extraction: thread slot (mi,ni,r) owns logit[row][col] ----
  {
    const int colbase = wn * 64 + (l & 15);
#pragma unroll
    for (int mi = 0; mi < 8; ++mi)
#pragma unroll
      for (int r = 0; r < 4; ++r) {
        const int row = wm * 128 + mi * 16 + (l >> 4) * 4 + r;
        int lab = larr[row];
        lab = lab < 0 ? 0 : (lab >= V_DIM ? V_DIM - 1 : lab);
        const int cl = lab - gn0;
#pragma unroll
        for (int ni = 0; ni < 4; ++ni)
          if (cl == colbase + ni * 16) tgt[m0 + row] = acc[mi][ni][r];
      }
  }

  // ---- epilogue: per-row sum of exp over this block's 256 cols ----
  float rs[8][4];
#pragma unroll
  for (int mi = 0; mi < 8; ++mi)
#pragma unroll
    for (int r = 0; r < 4; ++r) {
      float s = 0.f;
#pragma unroll
      for (int ni = 0; ni < 4; ++ni)
        s += exp2f(acc[mi][ni][r] * 1.4426950408889634f);
#pragma unroll
      for (int off = 1; off <= 8; off <<= 1) s += __shfl_xor(s, off, 64);
      rs[mi][r] = s;
    }
  __syncthreads();
  float* red = (float*)&Al[0][0];  // [4 wn][256 rows]
  if ((l & 15) == 0) {
#pragma unroll
    for (int mi = 0; mi < 8; ++mi)
#pragma unroll
      for (int r = 0; r < 4; ++r)
        red[wn * 256 + wm * 128 + mi * 16 + (l >> 4) * 4 + r] = rs[mi][r];
  }
  __syncthreads();
  if (tid < 256) {
    const float tot = (red[tid] + red[256 + tid]) + (red[512 + tid] + red[768 + tid]);
    partial[(size_t)(m0 + tid) * NPB + (c0 / 256 + (swz >> 3))] = tot;
  }
}

// ---------------- final reduce ----------------
__global__ __launch_bounds__(256) void reduce_lse(const float* __restrict__ partial,
                                                  const float* __restrict__ tgt,
                                                  const int* __restrict__ labels,
                                                  float* __restrict__ out) {
  const int row = blockIdx.x;
  float s = 0.f;
  for (int vb = threadIdx.x; vb < NPB; vb += 256)
    s += partial[(size_t)row * NPB + vb];
#pragma unroll
  for (int off = 1; off < 64; off <<= 1) s += __shfl_xor(s, off, 64);
  __shared__ float w4[4];
  if ((threadIdx.x & 63) == 0) w4[threadIdx.x >> 6] = s;
  __syncthreads();
  if (threadIdx.x == 0) {
    const float tot = (w4[0] + w4[1]) + (w4[2] + w4[3]);
    const float lse = logf(tot);
    const float loss = (labels[row] != -100) ? (lse - tgt[row]) : 0.f;
    out[row] = loss;
    out[M_DIM + row] = lse;
  }
}

extern "C" void kernel_launch(void* const* d_in, const int* in_sizes, int n_in,
                              void* d_out, int out_size, void* d_ws, size_t ws_size,
                              hipStream_t stream) {
  const float* x = (const float*)d_in[0];
  const float* wgt = (const float*)d_in[1];
  const int* labels = (const int*)d_in[2];
  float* out = (float*)d_out;

  char* ws = (char*)d_ws;
  unsigned short* xb = (unsigned short*)ws;
  size_t off = (size_t)M_DIM * K_DIM * 2;
  float* partial = (float*)(ws + off);
  off += (size_t)M_DIM * NPB * 4;
  float* tgt = (float*)(ws + off);
  off += (size_t)M_DIM * 4;
  off = (off + 255) & ~(size_t)255;
  unsigned short* wtc = (unsigned short*)(ws + off);
  const size_t avail = ws_size > off ? ws_size - off : 0;
  // CC=16384 (64 MB wtc chunk): LLC-resident between transpose and gemm.
  // Full-V wtc (525 MB) measured +270 us (HBM-latency-bound B); in-kernel
  // W-staging measured +700 us (round 9). Keep the chunked-LLC structure.
  int CC = 16384;
  while (CC > 256 && (size_t)CC * K_DIM * 2 > avail) CC >>= 1;

  cvt_x<<<dim3(M_DIM * K_DIM / (256 * 8)), dim3(256), 0, stream>>>(x, xb);
  for (int c0 = 0; c0 < V_DIM; c0 += CC) {
    int cc = V_DIM - c0;
    if (cc > CC) cc = CC;
    transpose_w<<<dim3(cc / 64, K_DIM / 64), dim3(256), 0, stream>>>(wgt, wtc, c0);
    const int nbx = cc / 256;
    gemm_lse<<<dim3(nbx * 8), dim3(512), 0, stream>>>(xb, wtc, labels, partial, tgt,
                                                      c0, nbx);
  }
  reduce_lse<<<dim3(M_DIM), dim3(256), 0, stream>>>(partial, tgt, labels, out);
}